// Round 7
// baseline (194.495 us; speedup 1.0000x reference)
//
#include <hip/hip_runtime.h>
#include <hip/hip_bf16.h>

typedef __bf16 bf16x8 __attribute__((ext_vector_type(8)));
typedef float  f32x4  __attribute__((ext_vector_type(4)));

#define MFMA16 __builtin_amdgcn_mfma_f32_16x16x32_bf16

__device__ __forceinline__ float fast_tanh(float x) {
    float e = __builtin_amdgcn_exp2f(x * 2.8853900817779268f);
    return 1.0f - 2.0f * __builtin_amdgcn_rcpf(e + 1.0f);
}

// kappa: GEMM1 epilogue writes h pairs at stored index s = 32w + 2c + nbl
// (phys col n = 32w + 16nbl + c). kinv(s) -> phys col, used for W2 rows.
__device__ __forceinline__ int kinv(int ke) {
    return (ke & ~31) | ((ke & 1) << 4) | ((ke >> 1) & 15);
}

__device__ __forceinline__ bf16x8 cvt2(const float4 a, const float4 b) {
    bf16x8 t;
    t[0] = (__bf16)a.x; t[1] = (__bf16)a.y; t[2] = (__bf16)a.z; t[3] = (__bf16)a.w;
    t[4] = (__bf16)b.x; t[5] = (__bf16)b.y; t[6] = (__bf16)b.z; t[7] = (__bf16)b.w;
    return t;
}
__device__ __forceinline__ unsigned short bfbits(__bf16 v) {
    return __builtin_bit_cast(unsigned short, v);
}

// M_TILE=128, 512 threads (8 waves), 128KB LDS, 1 block/CU, 256-VGPR cap.
// Weights live in registers (112 VGPR/lane). Swizzle (bijective, conflict-free
// for MFMA (row16,g) readers): byte(row,k) = 64*((k>>5)^(row&7)) + 16*((k>>3)&3) + 2*(k&7).
__global__ __launch_bounds__(512, 1) void rel_kernel(
    const float* __restrict__ fwd, const float* __restrict__ bwd,
    const int* __restrict__ gold_heads, const int* __restrict__ gold_rels,
    const float* __restrict__ WFOH, const float* __restrict__ WFOM,
    const float* __restrict__ rcatBias, const float* __restrict__ rhid2Layer,
    const float* __restrict__ rhid2Bias, const float* __restrict__ routLayer,
    const float* __restrict__ routBias,
    int* __restrict__ fixcnt, int* __restrict__ fixlist, int fixcap,
    float* __restrict__ out, int E, int NT)
{
    // LDS (aliased):
    //  [0,64K):    cat 128x256 bf16 (phys k) | h2 128x128 bf16 (identity cols)
    //  [64K,128K): h   128x256 bf16 (kappa)  | sc 128x64 f32
    __shared__ __align__(16) char smem[131072];
    char* const sh_cat = smem;
    char* const sh_h   = smem + 65536;
    char* const sh_h2  = smem;            // alias: cat dead after GEMM1 k-loop
    char* const sh_sc  = smem + 65536;    // alias: h dead after GEMM2 k-loop

    const int tid   = threadIdx.x;
    const int w     = tid >> 6;
    const int lane  = tid & 63;
    const int row16 = lane & 15;
    const int g     = lane >> 4;
    const int nw    = w & 3;        // GEMM3 label-block
    const int mh    = w >> 2;       // GEMM3 row-half

    const int r_s = tid >> 2;       // staging row (128)
    const int q_s = tid & 3;        // staging quarter (64 floats)

    // ---------------- persistent weights -> registers ----------------
    bf16x8 w1f[2][8];
    #pragma unroll
    for (int nbl = 0; nbl < 2; ++nbl) {
        const int n = 32 * w + 16 * nbl + row16;
        const float* Wsrc = (32 * w + 16 * nbl < 128) ? WFOH : WFOM;  // wave-uniform
        const int col = n & 127;
        #pragma unroll
        for (int kk = 0; kk < 8; ++kk) {
            bf16x8 f;
            #pragma unroll
            for (int j = 0; j < 8; ++j) f[j] = (__bf16)Wsrc[(32 * kk + 8 * g + j) * 128 + col];
            w1f[nbl][kk] = f;
        }
    }
    bf16x8 w2f[8];   // wave w owns h2-cols [16w,16w+16); k = kappa-stored h index
    {
        const int n2 = 16 * w + row16;
        #pragma unroll
        for (int kk = 0; kk < 8; ++kk) {
            bf16x8 f;
            #pragma unroll
            for (int j = 0; j < 8; ++j) f[j] = (__bf16)rhid2Layer[kinv(32 * kk + 8 * g + j) * 128 + n2];
            w2f[kk] = f;
        }
    }
    bf16x8 w3f[4];   // wave (mh,nw): labels [16nw,16nw+16); h2 stored at identity -> no perm
    {
        const int n3 = 16 * nw + row16;
        #pragma unroll
        for (int kk = 0; kk < 4; ++kk) {
            bf16x8 f;
            #pragma unroll
            for (int j = 0; j < 8; ++j) f[j] = (__bf16)routLayer[(32 * kk + 8 * g + j) * 64 + n3];
            w3f[kk] = f;
        }
    }
    const float rcb0 = rcatBias[32 * w + row16];
    const float rcb1 = rcatBias[32 * w + 16 + row16];
    const float r2b  = rhid2Bias[16 * w + row16];
    const float rob  = routBias[16 * nw + row16];

    // ---- prologue gather for first tile ----
    bf16x8 pfb[8];
    {
        const int e = blockIdx.x * 128 + r_s;
        int nh = 0;
        if (q_s < 2 && e < E) nh = gold_heads[e];
        if (e < E) {
            const float* src = (q_s < 2) ? (fwd + (size_t)nh * 128 + 64 * q_s)
                                         : (bwd + (size_t)(e + 1) * 128 + 64 * (q_s - 2));
            const float4* p4 = (const float4*)src;
            #pragma unroll
            for (int t = 0; t < 8; ++t) pfb[t] = cvt2(p4[2 * t], p4[2 * t + 1]);
        } else {
            #pragma unroll
            for (int t = 0; t < 8; ++t) pfb[t] = cvt2(make_float4(0.f,0.f,0.f,0.f), make_float4(0.f,0.f,0.f,0.f));
        }
    }

    for (int tile = blockIdx.x; tile < NT; tile += gridDim.x) {
        const int e0 = tile * 128;
        const int tnext = tile + gridDim.x;
        const bool hn = tnext < NT;

        // ---- stage cat tile (swizzled) ----
        #pragma unroll
        for (int t = 0; t < 8; ++t)
            *(bf16x8*)(sh_cat + r_s * 512
                       + 64 * ((2 * q_s + (t >> 2)) ^ (r_s & 7)) + 16 * (t & 3)) = pfb[t];

        // prefetch next head idx + this tile's gold label (used in hinge)
        int nh = 0; bool gv = false;
        if (hn) {
            const int en = tnext * 128 + r_s;
            gv = en < E;
            if (q_s < 2 && gv) nh = gold_heads[en];
        }
        int grel = 0;
        if (e0 + r_s < E) grel = gold_rels[e0 + r_s];
        __syncthreads();                                   // B1: cat ready

        // ---- GEMM1: h(128x256) = cat @ [WFOH|WFOM], tanh(+rcatBias) ----
        #pragma unroll
        for (int half = 0; half < 2; ++half) {
            f32x4 acc[4][2];
            #pragma unroll
            for (int i = 0; i < 4; ++i) {
                acc[i][0] = (f32x4){0.f, 0.f, 0.f, 0.f};
                acc[i][1] = (f32x4){0.f, 0.f, 0.f, 0.f};
            }
            #pragma unroll
            for (int kk = 0; kk < 8; ++kk) {
                const int kb = 64 * (kk ^ (row16 & 7)) + 16 * g;
                #pragma unroll
                for (int mb = 0; mb < 4; ++mb) {
                    const int row = 16 * (4 * half + mb) + row16;
                    const bf16x8 a = *(const bf16x8*)(sh_cat + row * 512 + kb);
                    acc[mb][0] = MFMA16(a, w1f[0][kk], acc[mb][0], 0, 0, 0);
                    acc[mb][1] = MFMA16(a, w1f[1][kk], acc[mb][1], 0, 0, 0);
                }
            }
            #pragma unroll
            for (int mb = 0; mb < 4; ++mb) {
                #pragma unroll
                for (int r = 0; r < 4; ++r) {
                    const int row = 16 * (4 * half + mb) + 4 * g + r;
                    const unsigned pk = (unsigned)bfbits((__bf16)fast_tanh(acc[mb][0][r] + rcb0))
                                      | ((unsigned)bfbits((__bf16)fast_tanh(acc[mb][1][r] + rcb1)) << 16);
                    *(unsigned*)(sh_h + row * 512 + 64 * (w ^ (row & 7))
                                 + 16 * (row16 >> 2) + 4 * (row16 & 3)) = pk;
                }
            }
        }
        __syncthreads();                                   // B2: h ready

        // ---- T14: issue next tile's gather batch A ----
        const float* gsrc = nullptr;
        if (hn) {
            const int en = tnext * 128 + r_s;
            gsrc = (q_s < 2) ? (fwd + (size_t)nh * 128 + 64 * q_s)
                             : (bwd + (size_t)(en + 1) * 128 + 64 * (q_s - 2));
        }
        float4 pfA[8];
        if (hn && gv) {
            const float4* p4 = (const float4*)gsrc;
            #pragma unroll
            for (int i = 0; i < 8; ++i) pfA[i] = p4[i];
        } else {
            #pragma unroll
            for (int i = 0; i < 8; ++i) pfA[i] = make_float4(0.f, 0.f, 0.f, 0.f);
        }

        // ---- GEMM2: h2(128x128) = h @ W2, tanh(+rhid2Bias) ----
        f32x4 acc2[8];
        #pragma unroll
        for (int i = 0; i < 8; ++i) acc2[i] = (f32x4){0.f, 0.f, 0.f, 0.f};
        #pragma unroll
        for (int kk = 0; kk < 8; ++kk) {
            const int kb = 64 * (kk ^ (row16 & 7)) + 16 * g;
            #pragma unroll
            for (int mb = 0; mb < 8; ++mb) {
                const bf16x8 a = *(const bf16x8*)(sh_h + (16 * mb + row16) * 512 + kb);
                acc2[mb] = MFMA16(a, w2f[kk], acc2[mb], 0, 0, 0);
            }
        }
        // convert A -> pfb[0..3]; issue batch B
        #pragma unroll
        for (int t = 0; t < 4; ++t) pfb[t] = cvt2(pfA[2 * t], pfA[2 * t + 1]);
        float4 pfB[8];
        if (hn && gv) {
            const float4* p4 = (const float4*)gsrc;
            #pragma unroll
            for (int i = 0; i < 8; ++i) pfB[i] = p4[8 + i];
        } else {
            #pragma unroll
            for (int i = 0; i < 8; ++i) pfB[i] = make_float4(0.f, 0.f, 0.f, 0.f);
        }
        // h2 epilogue: identity col p = 16w+row16; g-mixed swizzle
        {
            const int kk2w = w >> 1;
            const int g2 = (2 * w + (row16 >> 3)) & 3;
            #pragma unroll
            for (int mb = 0; mb < 8; ++mb) {
                #pragma unroll
                for (int r = 0; r < 4; ++r) {
                    const int row = 16 * mb + 4 * g + r;
                    const __bf16 p = (__bf16)fast_tanh(acc2[mb][r] + r2b);
                    *(unsigned short*)(sh_h2 + row * 256
                        + 64 * (kk2w ^ (row & 3))
                        + 16 * (g2 ^ ((row >> 2) & 3))
                        + 2 * (row16 & 7)) = bfbits(p);
                }
            }
        }
        __syncthreads();                                   // B3: h2 ready

        // ---- GEMM3: sc(128x64) = h2 @ W3 + routBias ----
        f32x4 acc3[4];
        #pragma unroll
        for (int i = 0; i < 4; ++i) acc3[i] = (f32x4){0.f, 0.f, 0.f, 0.f};
        #pragma unroll
        for (int kk = 0; kk < 4; ++kk) {
            const int kb = 64 * (kk ^ (row16 & 3)) + 16 * (g ^ ((row16 >> 2) & 3));
            #pragma unroll
            for (int mb = 0; mb < 4; ++mb) {
                const int row = 64 * mh + 16 * mb + row16;
                const bf16x8 a = *(const bf16x8*)(sh_h2 + row * 256 + kb);
                acc3[mb] = MFMA16(a, w3f[kk], acc3[mb], 0, 0, 0);
            }
        }
        // convert B -> pfb[4..7]
        #pragma unroll
        for (int t = 0; t < 4; ++t) pfb[4 + t] = cvt2(pfB[2 * t], pfB[2 * t + 1]);
        #pragma unroll
        for (int mb = 0; mb < 4; ++mb) {
            #pragma unroll
            for (int r = 0; r < 4; ++r) {
                const int row = 64 * mh + 16 * mb + 4 * g + r;
                *(float*)(sh_sc + row * 256
                          + ((64 * nw + 4 * row16) ^ ((row & 7) << 4))) = acc3[mb][r] + rob;
            }
        }
        __syncthreads();                                   // B4: sc ready

        // ---- hinge: 4 threads per edge row; boundary -> global fixlist ----
        {
            const int r = tid >> 2, q = tid & 3;
            const int e = e0 + r;
            const int gold = grel;
            float gs = -3.0e38f, ws_ = -3.0e38f;
            #pragma unroll
            for (int c = 0; c < 4; ++c) {
                const f32x4 sv = *(const f32x4*)(sh_sc + r * 256
                                   + ((64 * q + 16 * c) ^ ((r & 7) << 4)));
                #pragma unroll
                for (int cc = 0; cc < 4; ++cc) {
                    const int lab = 16 * q + 4 * c + cc;
                    const float v = sv[cc];
                    if (lab == gold) gs = v; else ws_ = fmaxf(ws_, v);
                }
            }
            gs = fmaxf(gs, __shfl_xor(gs, 1)); ws_ = fmaxf(ws_, __shfl_xor(ws_, 1));
            gs = fmaxf(gs, __shfl_xor(gs, 2)); ws_ = fmaxf(ws_, __shfl_xor(ws_, 2));
            if (q == 0 && e < E) {
                out[e] = (gs < ws_ + 1.0f) ? (ws_ - gs) : 0.0f;
                // hinge discontinuous at margin==1 -> exact f32 recompute later
                if (fabsf((gs - ws_) - 1.0f) < 0.125f && fixcap > 0) {
                    const int idx = atomicAdd(fixcnt, 1);
                    if (idx < fixcap) fixlist[idx] = e;
                }
            }
        }
        // no barrier: next-loop staging touches cat(=h2, dead since B4);
        // next B1 orders hinge's sc reads vs next GEMM1's h writes.
    }
}

// ---- exact f32 recompute of margin-boundary edges (~1e-3 of edges) ----
__global__ __launch_bounds__(256) void fixup_kernel(
    const float* __restrict__ fwd, const float* __restrict__ bwd,
    const int* __restrict__ gold_heads, const int* __restrict__ gold_rels,
    const float* __restrict__ WFOH, const float* __restrict__ WFOM,
    const float* __restrict__ rcatBias, const float* __restrict__ rhid2Layer,
    const float* __restrict__ rhid2Bias, const float* __restrict__ routLayer,
    const float* __restrict__ routBias,
    const int* __restrict__ fixcnt, const int* __restrict__ fixlist, int fixcap,
    float* __restrict__ out)
{
    __shared__ float fx_cat[256];
    __shared__ float fx_h[256];
    __shared__ float fx_h2[128];
    __shared__ float fx_p[256];
    int n = *fixcnt;
    if (n > fixcap) n = fixcap;
    const int tid = threadIdx.x;
    for (int i = blockIdx.x; i < n; i += gridDim.x) {
        const int e = fixlist[i];
        {
            const int head = gold_heads[e];
            fx_cat[tid] = (tid < 128) ? fwd[(size_t)head * 128 + tid]
                                      : bwd[(size_t)(e + 1) * 128 + (tid - 128)];
        }
        __syncthreads();
        {
            const float* base = (tid < 128) ? WFOH : WFOM;
            const int col = tid & 127;
            float s = 0.f;
            #pragma unroll 8
            for (int k = 0; k < 256; ++k) s += fx_cat[k] * base[k * 128 + col];
            fx_h[tid] = tanhf(s + rcatBias[tid]);
        }
        __syncthreads();
        {
            const int d = tid & 127, hh = tid >> 7;
            float s = 0.f;
            #pragma unroll 8
            for (int k = 128 * hh; k < 128 * hh + 128; ++k) s += fx_h[k] * rhid2Layer[k * 128 + d];
            fx_p[hh * 128 + d] = s;
        }
        __syncthreads();
        if (tid < 128) fx_h2[tid] = tanhf(fx_p[tid] + fx_p[128 + tid] + rhid2Bias[tid]);
        __syncthreads();
        {
            const int d = tid & 63, qq = tid >> 6;
            float s = 0.f;
            #pragma unroll 8
            for (int k = 32 * qq; k < 32 * qq + 32; ++k) s += fx_h2[k] * routLayer[k * 64 + d];
            fx_p[qq * 64 + d] = s;
        }
        __syncthreads();
        if (tid < 64) {
            const float v = fx_p[tid] + fx_p[64 + tid] + fx_p[128 + tid] + fx_p[192 + tid] + routBias[tid];
            const int gold = gold_rels[e];
            float gs = (tid == gold) ? v : -3.0e38f;
            float wv = (tid == gold) ? -3.0e38f : v;
            #pragma unroll
            for (int o = 1; o < 64; o <<= 1) {
                gs = fmaxf(gs, __shfl_xor(gs, o));
                wv = fmaxf(wv, __shfl_xor(wv, o));
            }
            if (tid == 0) out[e] = (gs < wv + 1.0f) ? (wv - gs) : 0.0f;
        }
        __syncthreads();
    }
}

extern "C" void kernel_launch(void* const* d_in, const int* in_sizes, int n_in,
                              void* d_out, int out_size, void* d_ws, size_t ws_size,
                              hipStream_t stream) {
    const float* fwd        = (const float*)d_in[0];
    const float* bwd        = (const float*)d_in[1];
    const int*   gold_heads = (const int*)d_in[2];
    const int*   gold_rels  = (const int*)d_in[3];
    const float* WFOH       = (const float*)d_in[4];
    const float* WFOM       = (const float*)d_in[5];
    const float* rcatBias   = (const float*)d_in[7];   // d_in[6] rhidBias unused by reference
    const float* rhid2      = (const float*)d_in[8];
    const float* rhid2Bias  = (const float*)d_in[9];
    const float* rout       = (const float*)d_in[10];
    const float* routBias   = (const float*)d_in[11];
    float* out = (float*)d_out;

    const int E = in_sizes[2];
    if (E <= 0) return;
    const int NT = (E + 127) / 128;
    const int grid = NT < 256 ? NT : 256;

    const int FIXCAP = 8192;
    const size_t FIX_BYTES = 4 + 4 * (size_t)FIXCAP;
    int* fixcnt = nullptr;
    int* fixlist = nullptr;
    int fixcap = 0;
    if (ws_size >= FIX_BYTES) {
        fixcnt = (int*)d_ws;
        fixlist = fixcnt + 1;
        fixcap = FIXCAP;
        hipMemsetAsync(fixcnt, 0, 4, stream);
    }

    hipLaunchKernelGGL(rel_kernel, dim3(grid), dim3(512), 0, stream,
                       fwd, bwd, gold_heads, gold_rels, WFOH, WFOM, rcatBias,
                       rhid2, rhid2Bias, rout, routBias,
                       fixcnt, fixlist, fixcap, out, E, NT);
    if (fixcap) {
        hipLaunchKernelGGL(fixup_kernel, dim3(120), dim3(256), 0, stream,
                           fwd, bwd, gold_heads, gold_rels, WFOH, WFOM, rcatBias,
                           rhid2, rhid2Bias, rout, routBias,
                           fixcnt, fixlist, fixcap, out);
    }
}

// Round 8
// 185.356 us; speedup vs baseline: 1.0493x; 1.0493x over previous
//
#include <hip/hip_runtime.h>
#include <hip/hip_bf16.h>

typedef __bf16 bf16x8 __attribute__((ext_vector_type(8)));
typedef float  f32x4  __attribute__((ext_vector_type(4)));

#define MFMA16 __builtin_amdgcn_mfma_f32_16x16x32_bf16

__device__ __forceinline__ float fast_tanh(float x) {
    float e = __builtin_amdgcn_exp2f(x * 2.8853900817779268f);
    return 1.0f - 2.0f * __builtin_amdgcn_rcpf(e + 1.0f);
}

// kappa permutation: stored k-index s -> physical k-dim
__device__ __forceinline__ int kinv(int ke) {
    return (ke & ~31) | ((ke & 1) << 4) | ((ke >> 1) & 15);
}

__device__ __forceinline__ bf16x8 cvt2(const float4 a, const float4 b) {
    bf16x8 t;
    t[0] = (__bf16)a.x; t[1] = (__bf16)a.y; t[2] = (__bf16)a.z; t[3] = (__bf16)a.w;
    t[4] = (__bf16)b.x; t[5] = (__bf16)b.y; t[6] = (__bf16)b.z; t[7] = (__bf16)b.w;
    return t;
}

// ---- weight pre-conversion: f32 -> bf16 MFMA B-fragments in d_ws ----
// table1 ws[0,131072):      [w:8][kk:8][nbl:2][lane:64][j:8 bf16]   (GEMM1)
// table2 ws[131072,196608): [q4:4][kk:8][nbl:2][lane:64][j:8]       (GEMM2, kappa rows)
// table3 ws[196608,212992): [nb:4][kk:4][lane:64][j:8]              (GEMM3, kappa rows)
__global__ __launch_bounds__(256) void preconv_kernel(
    const float* __restrict__ WFOH, const float* __restrict__ WFOM,
    const float* __restrict__ rhid2Layer, const float* __restrict__ routLayer,
    char* __restrict__ ws)
{
    const int f = blockIdx.x * 256 + threadIdx.x;
    bf16x8 v;
    char* dst;
    if (f < 8192) {
        const int lane = f & 63, t = f >> 6;
        const int nbl = t & 1, kk = (t >> 1) & 7, w = t >> 4;
        const int g = lane >> 4, c = lane & 15;
        const int nb = 32 * w + 16 * nbl;
        const float* Wsrc = (nb < 128) ? WFOH : WFOM;
        const int col = (nb + c) & 127;
        #pragma unroll
        for (int j = 0; j < 8; ++j) v[j] = (__bf16)Wsrc[(32 * kk + 8 * g + j) * 128 + col];
        dst = ws + (size_t)f * 16;
    } else if (f < 12288) {
        const int f2 = f - 8192;
        const int lane = f2 & 63, t = f2 >> 6;
        const int nbl = t & 1, kk = (t >> 1) & 7, q4 = t >> 4;
        const int g = lane >> 4, c = lane & 15;
        const int n2 = 32 * q4 + 16 * nbl + c;
        #pragma unroll
        for (int j = 0; j < 8; ++j) v[j] = (__bf16)rhid2Layer[kinv(32 * kk + 8 * g + j) * 128 + n2];
        dst = ws + 131072 + (size_t)f2 * 16;
    } else if (f < 13312) {
        const int f3 = f - 12288;
        const int lane = f3 & 63, t = f3 >> 6;
        const int kk = t & 3, q4 = t >> 2;
        const int g = lane >> 4, c = lane & 15;
        const int n3 = 16 * q4 + c;
        #pragma unroll
        for (int j = 0; j < 8; ++j) v[j] = (__bf16)routLayer[kinv(32 * kk + 8 * g + j) * 64 + n3];
        dst = ws + 196608 + (size_t)f3 * 16;
    } else {
        return;
    }
    *(bf16x8*)dst = v;
}

template<bool PRE>
__device__ __forceinline__ bf16x8 wfrag1(const char* ws, const float* WFOH, const float* WFOM,
                                         int w, int kk, int nbl, int lane) {
    if constexpr (PRE) {
        return *(const bf16x8*)(ws + (size_t)w * 16384 + kk * 2048 + nbl * 1024 + lane * 16);
    } else {
        const int g = lane >> 4, c = lane & 15;
        const int nb = 32 * w + 16 * nbl;
        const float* Wsrc = (nb < 128) ? WFOH : WFOM;
        const int col = (nb + c) & 127;
        bf16x8 v;
        #pragma unroll
        for (int j = 0; j < 8; ++j) v[j] = (__bf16)Wsrc[(32 * kk + 8 * g + j) * 128 + col];
        return v;
    }
}
template<bool PRE>
__device__ __forceinline__ bf16x8 wfrag2(const char* ws, const float* rhid2Layer,
                                         int q4, int kk, int nbl, int lane) {
    if constexpr (PRE) {
        return *(const bf16x8*)(ws + 131072 + (size_t)q4 * 16384 + kk * 2048 + nbl * 1024 + lane * 16);
    } else {
        const int g = lane >> 4, c = lane & 15;
        const int n2 = 32 * q4 + 16 * nbl + c;
        bf16x8 v;
        #pragma unroll
        for (int j = 0; j < 8; ++j) v[j] = (__bf16)rhid2Layer[kinv(32 * kk + 8 * g + j) * 128 + n2];
        return v;
    }
}
template<bool PRE>
__device__ __forceinline__ bf16x8 wfrag3(const char* ws, const float* routLayer,
                                         int nb, int kk, int lane) {
    if constexpr (PRE) {
        return *(const bf16x8*)(ws + 196608 + (size_t)nb * 4096 + kk * 1024 + lane * 16);
    } else {
        const int g = lane >> 4, c = lane & 15;
        const int n3 = 16 * nb + c;
        bf16x8 v;
        #pragma unroll
        for (int j = 0; j < 8; ++j) v[j] = (__bf16)routLayer[kinv(32 * kk + 8 * g + j) * 64 + n3];
        return v;
    }
}

// M_TILE=64, 512 threads (8 waves), 80KB LDS -> 2 blocks/CU, VGPR cap 128.
// 3 barriers/tile; GEMM3+hinge fully in-wave (waves 0-3); k-loops fully
// unrolled with inline frag loads (compiler pipelines); per-tile pointer
// launder prevents cross-tile frag hoisting (the R7 spill).
template<bool PRE>
__global__ __launch_bounds__(512, 2) void rel_kernel(
    const float* __restrict__ fwd, const float* __restrict__ bwd,
    const int* __restrict__ gold_heads, const int* __restrict__ gold_rels,
    const float* __restrict__ WFOH, const float* __restrict__ WFOM,
    const float* __restrict__ rcatBias, const float* __restrict__ rhid2Layer,
    const float* __restrict__ rhid2Bias, const float* __restrict__ routLayer,
    const float* __restrict__ routBias, const char* __restrict__ wstab,
    int* __restrict__ fixcnt, int* __restrict__ fixlist, int fixcap,
    float* __restrict__ out, int E, int NT)
{
    // LDS, no aliasing: cat 64x256 bf16 [0,32K) | h 64x256 kappa [32K,64K)
    //                   | h2 64x128 [64K,80K)
    __shared__ __align__(16) char smem[81920];
    char* const sh_cat = smem;
    char* const sh_h   = smem + 32768;
    char* const sh_h2  = smem + 65536;

    const int tid   = threadIdx.x;
    const int w     = tid >> 6;
    const int lane  = tid & 63;
    const int row16 = lane & 15;
    const int g     = lane >> 4;
    const int xm    = (row16 & 7) << 4;

    const int r_s = tid >> 3;       // staging row (64 rows)
    const int q_s = tid & 7;        // staging eighth (32 floats)
    const int xr  = (r_s & 7) << 4;

    const float rcb0 = rcatBias[32 * w + row16];
    const float rcb1 = rcatBias[32 * w + 16 + row16];
    const float r2b  = rhid2Bias[16 * w + row16];
    float rob[4];
    #pragma unroll
    for (int nb = 0; nb < 4; ++nb) rob[nb] = routBias[16 * nb + row16];

    // ---- prologue gather for first tile ----
    bf16x8 pfb[4];
    {
        const int e = blockIdx.x * 64 + r_s;
        int nh0 = 0;
        if (q_s < 4 && e < E) nh0 = gold_heads[e];
        if (e < E) {
            const float* src = (q_s < 4) ? (fwd + (size_t)nh0 * 128 + 32 * q_s)
                                         : (bwd + (size_t)(e + 1) * 128 + 32 * (q_s - 4));
            const float4* p4 = (const float4*)src;
            #pragma unroll
            for (int i = 0; i < 4; ++i) pfb[i] = cvt2(p4[2 * i], p4[2 * i + 1]);
        } else {
            #pragma unroll
            for (int i = 0; i < 4; ++i) pfb[i] = cvt2(make_float4(0.f,0.f,0.f,0.f), make_float4(0.f,0.f,0.f,0.f));
        }
    }

    for (int tile = blockIdx.x; tile < NT; tile += gridDim.x) {
        const int e0 = tile * 64;
        const int tnext = tile + gridDim.x;
        const bool hn = tnext < NT;

        // opaque-zero launder: weight pointers become tile-dependent, so the
        // compiler cannot hoist all frag loads out of the tile loop (R7 spill).
        int zoff = 0;
        asm volatile("" : "+v"(zoff));
        const char*  wsL  = wstab + zoff;
        const float* W1aL = WFOH + zoff;
        const float* W1bL = WFOM + zoff;
        const float* W2L  = rhid2Layer + zoff;
        const float* W3L  = routLayer + zoff;

        // next tile's head index first (latency overlaps staging + B1 wait)
        int nh = 0; bool gv = false;
        if (hn) {
            const int en = tnext * 64 + r_s;
            gv = en < E;
            if (q_s < 4 && gv) nh = gold_heads[en];
        }

        // ---- stage cat tile (bf16, swizzled) from pfb ----
        #pragma unroll
        for (int i = 0; i < 4; ++i)
            *(bf16x8*)(sh_cat + r_s * 512 + ((64 * q_s + 16 * i) ^ xr)) = pfb[i];

        // gold labels for this tile (hinge rows 16w + 4g + i)
        int gr[4] = {0, 0, 0, 0};
        if (w < 4) {
            #pragma unroll
            for (int i = 0; i < 4; ++i) {
                const int e = e0 + 16 * w + 4 * g + i;
                if (e < E) gr[i] = gold_rels[e];
            }
        }
        __syncthreads();                                   // B1: cat ready

        // ---- issue next tile's row gathers now; cvt before B3 ----
        float4 pfA[8];
        if (hn && gv) {
            const float4* p4 = (const float4*)((q_s < 4)
                                 ? (fwd + (size_t)nh * 128 + 32 * q_s)
                                 : (bwd + (size_t)(tnext * 64 + r_s + 1) * 128 + 32 * (q_s - 4)));
            #pragma unroll
            for (int i = 0; i < 8; ++i) pfA[i] = p4[i];
        } else {
            #pragma unroll
            for (int i = 0; i < 8; ++i) pfA[i] = make_float4(0.f, 0.f, 0.f, 0.f);
        }

        // ---- GEMM1: h(64x256) = cat @ [WFOH|WFOM], tanh(+rcatBias) ----
        f32x4 acc1[4][2];
        #pragma unroll
        for (int i = 0; i < 4; ++i) {
            acc1[i][0] = (f32x4){0.f, 0.f, 0.f, 0.f};
            acc1[i][1] = (f32x4){0.f, 0.f, 0.f, 0.f};
        }
        #pragma unroll
        for (int kk = 0; kk < 8; ++kk) {
            const bf16x8 b0 = wfrag1<PRE>(wsL, W1aL, W1bL, w, kk, 0, lane);
            const bf16x8 b1 = wfrag1<PRE>(wsL, W1aL, W1bL, w, kk, 1, lane);
            const int ko = (64 * kk + 16 * g) ^ xm;
            #pragma unroll
            for (int mb = 0; mb < 4; ++mb) {
                const bf16x8 a = *(const bf16x8*)(sh_cat + (16 * mb + row16) * 512 + ko);
                acc1[mb][0] = MFMA16(a, b0, acc1[mb][0], 0, 0, 0);
                acc1[mb][1] = MFMA16(a, b1, acc1[mb][1], 0, 0, 0);
            }
        }
        #pragma unroll
        for (int mb = 0; mb < 4; ++mb) {
            #pragma unroll
            for (int r = 0; r < 4; ++r) {
                const int row = 16 * mb + 4 * g + r;
                const __bf16 p0 = (__bf16)fast_tanh(acc1[mb][0][r] + rcb0);
                const __bf16 p1 = (__bf16)fast_tanh(acc1[mb][1][r] + rcb1);
                const unsigned u = (unsigned)__builtin_bit_cast(unsigned short, p0)
                                 | ((unsigned)__builtin_bit_cast(unsigned short, p1) << 16);
                *(unsigned*)(sh_h + row * 512 + ((64 * w + 4 * row16) ^ ((row & 7) << 4))) = u;
            }
        }
        __syncthreads();                                   // B2: h ready

        // ---- GEMM2: h2(64x128) = h @ W2(kappa), tanh(+rhid2Bias) ----
        f32x4 acc2[4];
        #pragma unroll
        for (int i = 0; i < 4; ++i) acc2[i] = (f32x4){0.f, 0.f, 0.f, 0.f};
        #pragma unroll
        for (int kk = 0; kk < 8; ++kk) {
            const bf16x8 b2 = wfrag2<PRE>(wsL, W2L, w >> 1, kk, w & 1, lane);
            const int ko = (64 * kk + 16 * g) ^ xm;
            #pragma unroll
            for (int mb = 0; mb < 4; ++mb) {
                const bf16x8 a = *(const bf16x8*)(sh_h + (16 * mb + row16) * 512 + ko);
                acc2[mb] = MFMA16(a, b2, acc2[mb], 0, 0, 0);
            }
        }
        #pragma unroll
        for (int mb = 0; mb < 4; ++mb) {
            #pragma unroll
            for (int r = 0; r < 4; ++r) {
                const int row = 16 * mb + 4 * g + r;
                const __bf16 p = (__bf16)fast_tanh(acc2[mb][r] + r2b);
                *(unsigned short*)(sh_h2 + row * 256 +
                    ((64 * (w >> 1) + 4 * row16 + 2 * (w & 1)) ^ ((row & 7) << 4)))
                    = __builtin_bit_cast(unsigned short, p);
            }
        }
        // convert next-tile gather -> pfb (pfA issued before GEMM1: landed)
        #pragma unroll
        for (int i = 0; i < 4; ++i) pfb[i] = cvt2(pfA[2 * i], pfA[2 * i + 1]);
        __syncthreads();                                   // B3: h2 ready

        // ---- GEMM3 + hinge fully in-wave (waves 0-3; 16 rows x 64 labels) ----
        if (w < 4) {
            bf16x8 a3[4];
            #pragma unroll
            for (int kk = 0; kk < 4; ++kk)
                a3[kk] = *(const bf16x8*)(sh_h2 + (16 * w + row16) * 256 + ((64 * kk + 16 * g) ^ xm));
            f32x4 acc3[4];
            #pragma unroll
            for (int nb = 0; nb < 4; ++nb) {
                acc3[nb] = (f32x4){0.f, 0.f, 0.f, 0.f};
                #pragma unroll
                for (int kk = 0; kk < 4; ++kk) {
                    const bf16x8 b = wfrag3<PRE>(wsL, W3L, nb, kk, lane);
                    acc3[nb] = MFMA16(a3[kk], b, acc3[nb], 0, 0, 0);
                }
            }
            #pragma unroll
            for (int i = 0; i < 4; ++i) {
                const int gold = gr[i];
                float gs = -3.0e38f, ws_ = -3.0e38f;
                #pragma unroll
                for (int nb = 0; nb < 4; ++nb) {
                    const float v = acc3[nb][i] + rob[nb];
                    const int lab = 16 * nb + row16;
                    if (lab == gold) gs = v; else ws_ = fmaxf(ws_, v);
                }
                gs = fmaxf(gs, __shfl_xor(gs, 1)); ws_ = fmaxf(ws_, __shfl_xor(ws_, 1));
                gs = fmaxf(gs, __shfl_xor(gs, 2)); ws_ = fmaxf(ws_, __shfl_xor(ws_, 2));
                gs = fmaxf(gs, __shfl_xor(gs, 4)); ws_ = fmaxf(ws_, __shfl_xor(ws_, 4));
                gs = fmaxf(gs, __shfl_xor(gs, 8)); ws_ = fmaxf(ws_, __shfl_xor(ws_, 8));
                const int e = e0 + 16 * w + 4 * g + i;
                if (row16 == 0 && e < E) {
                    out[e] = (gs < ws_ + 1.0f) ? (ws_ - gs) : 0.0f;
                    // hinge discontinuous at margin==1 -> exact f32 recompute
                    if (fabsf((gs - ws_) - 1.0f) < 0.125f && fixcap > 0) {
                        const int idx = atomicAdd(fixcnt, 1);
                        if (idx < fixcap) fixlist[idx] = e;
                    }
                }
            }
        }
        // no end barrier: loop-top staging writes cat (dead since B2);
        // B1' orders staging vs all readers.
    }
}

// ---- exact f32 recompute of margin-boundary edges (~1e-3 of edges) ----
__global__ __launch_bounds__(256) void fixup_kernel(
    const float* __restrict__ fwd, const float* __restrict__ bwd,
    const int* __restrict__ gold_heads, const int* __restrict__ gold_rels,
    const float* __restrict__ WFOH, const float* __restrict__ WFOM,
    const float* __restrict__ rcatBias, const float* __restrict__ rhid2Layer,
    const float* __restrict__ rhid2Bias, const float* __restrict__ routLayer,
    const float* __restrict__ routBias,
    const int* __restrict__ fixcnt, const int* __restrict__ fixlist, int fixcap,
    float* __restrict__ out)
{
    __shared__ float fx_cat[256];
    __shared__ float fx_h[256];
    __shared__ float fx_h2[128];
    __shared__ float fx_p[256];
    int n = *fixcnt;
    if (n > fixcap) n = fixcap;
    const int tid = threadIdx.x;
    for (int i = blockIdx.x; i < n; i += gridDim.x) {
        const int e = fixlist[i];
        {
            const int head = gold_heads[e];
            fx_cat[tid] = (tid < 128) ? fwd[(size_t)head * 128 + tid]
                                      : bwd[(size_t)(e + 1) * 128 + (tid - 128)];
        }
        __syncthreads();
        {
            const float* base = (tid < 128) ? WFOH : WFOM;
            const int col = tid & 127;
            float s = 0.f;
            #pragma unroll 8
            for (int k = 0; k < 256; ++k) s += fx_cat[k] * base[k * 128 + col];
            fx_h[tid] = tanhf(s + rcatBias[tid]);
        }
        __syncthreads();
        {
            const int d = tid & 127, hh = tid >> 7;
            float s = 0.f;
            #pragma unroll 8
            for (int k = 128 * hh; k < 128 * hh + 128; ++k) s += fx_h[k] * rhid2Layer[k * 128 + d];
            fx_p[hh * 128 + d] = s;
        }
        __syncthreads();
        if (tid < 128) fx_h2[tid] = tanhf(fx_p[tid] + fx_p[128 + tid] + rhid2Bias[tid]);
        __syncthreads();
        {
            const int d = tid & 63, qq = tid >> 6;
            float s = 0.f;
            #pragma unroll 8
            for (int k = 32 * qq; k < 32 * qq + 32; ++k) s += fx_h2[k] * routLayer[k * 64 + d];
            fx_p[qq * 64 + d] = s;
        }
        __syncthreads();
        if (tid < 64) {
            const float v = fx_p[tid] + fx_p[64 + tid] + fx_p[128 + tid] + fx_p[192 + tid] + routBias[tid];
            const int gold = gold_rels[e];
            float gs = (tid == gold) ? v : -3.0e38f;
            float wv = (tid == gold) ? -3.0e38f : v;
            #pragma unroll
            for (int o = 1; o < 64; o <<= 1) {
                gs = fmaxf(gs, __shfl_xor(gs, o));
                wv = fmaxf(wv, __shfl_xor(wv, o));
            }
            if (tid == 0) out[e] = (gs < wv + 1.0f) ? (wv - gs) : 0.0f;
        }
        __syncthreads();
    }
}

extern "C" void kernel_launch(void* const* d_in, const int* in_sizes, int n_in,
                              void* d_out, int out_size, void* d_ws, size_t ws_size,
                              hipStream_t stream) {
    const float* fwd        = (const float*)d_in[0];
    const float* bwd        = (const float*)d_in[1];
    const int*   gold_heads = (const int*)d_in[2];
    const int*   gold_rels  = (const int*)d_in[3];
    const float* WFOH       = (const float*)d_in[4];
    const float* WFOM       = (const float*)d_in[5];
    const float* rcatBias   = (const float*)d_in[7];   // d_in[6] rhidBias unused by reference
    const float* rhid2      = (const float*)d_in[8];
    const float* rhid2Bias  = (const float*)d_in[9];
    const float* rout       = (const float*)d_in[10];
    const float* routBias   = (const float*)d_in[11];
    float* out = (float*)d_out;

    const int E = in_sizes[2];
    if (E <= 0) return;
    const int NT = (E + 63) / 64;
    const int grid = NT < 512 ? NT : 512;

    const size_t TAB = 212992;
    const int FIXCAP = 8192;
    const size_t FIX_BYTES = 4 + 4 * (size_t)FIXCAP;

    const bool pre = ws_size >= TAB + FIX_BYTES;
    int* fixcnt = nullptr;
    int* fixlist = nullptr;
    int fixcap = 0;
    if (pre) {
        fixcnt = (int*)((char*)d_ws + TAB);
        fixlist = fixcnt + 1;
        fixcap = FIXCAP;
    } else if (ws_size >= FIX_BYTES) {
        fixcnt = (int*)d_ws;
        fixlist = fixcnt + 1;
        fixcap = FIXCAP;
    }
    if (fixcap) hipMemsetAsync(fixcnt, 0, 4, stream);

    if (pre) {
        hipLaunchKernelGGL(preconv_kernel, dim3(52), dim3(256), 0, stream,
                           WFOH, WFOM, rhid2, rout, (char*)d_ws);
        hipLaunchKernelGGL((rel_kernel<true>), dim3(grid), dim3(512), 0, stream,
                           fwd, bwd, gold_heads, gold_rels, WFOH, WFOM, rcatBias,
                           rhid2, rhid2Bias, rout, routBias, (const char*)d_ws,
                           fixcnt, fixlist, fixcap, out, E, NT);
    } else {
        hipLaunchKernelGGL((rel_kernel<false>), dim3(grid), dim3(512), 0, stream,
                           fwd, bwd, gold_heads, gold_rels, WFOH, WFOM, rcatBias,
                           rhid2, rhid2Bias, rout, routBias, (const char*)nullptr,
                           fixcnt, fixlist, fixcap, out, E, NT);
    }
    if (fixcap) {
        hipLaunchKernelGGL(fixup_kernel, dim3(120), dim3(256), 0, stream,
                           fwd, bwd, gold_heads, gold_rels, WFOH, WFOM, rcatBias,
                           rhid2, rhid2Bias, rout, routBias,
                           fixcnt, fixlist, fixcap, out);
    }
}

// Round 9
// 176.948 us; speedup vs baseline: 1.0992x; 1.0475x over previous
//
#include <hip/hip_runtime.h>
#include <hip/hip_bf16.h>

typedef __bf16 bf16x8 __attribute__((ext_vector_type(8)));
typedef float  f32x4  __attribute__((ext_vector_type(4)));

#define MFMA16 __builtin_amdgcn_mfma_f32_16x16x32_bf16

__device__ __forceinline__ float fast_tanh(float x) {
    float e = __builtin_amdgcn_exp2f(x * 2.8853900817779268f);
    return 1.0f - 2.0f * __builtin_amdgcn_rcpf(e + 1.0f);
}

// kappa permutation for h storage: stored k-index s -> physical h column
__device__ __forceinline__ int kinv(int ke) {
    return (ke & ~31) | ((ke & 1) << 4) | ((ke >> 1) & 15);
}

__device__ __forceinline__ bf16x8 cvt2(const float4 a, const float4 b) {
    bf16x8 t;
    t[0] = (__bf16)a.x; t[1] = (__bf16)a.y; t[2] = (__bf16)a.z; t[3] = (__bf16)a.w;
    t[4] = (__bf16)b.x; t[5] = (__bf16)b.y; t[6] = (__bf16)b.z; t[7] = (__bf16)b.w;
    return t;
}

// ---- weight pre-conversion: f32 -> bf16 MFMA B-fragments in d_ws ----
// table1 ws[0,131072):      [w:8][kk:8][nbl:2][lane:64][j:8 bf16]   (GEMM1, phys rows)
// table2 ws[131072,196608): [q4:4][kk:8][nbl:2][lane:64][j:8]       (GEMM2, kappa rows)
// table3 ws[196608,212992): [nb:4][kk:4][lane:64][j:8]              (GEMM3, IDENTITY rows)
__global__ __launch_bounds__(256) void preconv_kernel(
    const float* __restrict__ WFOH, const float* __restrict__ WFOM,
    const float* __restrict__ rhid2Layer, const float* __restrict__ routLayer,
    char* __restrict__ ws)
{
    const int f = blockIdx.x * 256 + threadIdx.x;
    bf16x8 v;
    char* dst;
    if (f < 8192) {
        const int lane = f & 63, t = f >> 6;
        const int nbl = t & 1, kk = (t >> 1) & 7, w = t >> 4;
        const int g = lane >> 4, c = lane & 15;
        const int nb = 32 * w + 16 * nbl;
        const float* Wsrc = (nb < 128) ? WFOH : WFOM;
        const int col = (nb + c) & 127;
        #pragma unroll
        for (int j = 0; j < 8; ++j) v[j] = (__bf16)Wsrc[(32 * kk + 8 * g + j) * 128 + col];
        dst = ws + (size_t)f * 16;
    } else if (f < 12288) {
        const int f2 = f - 8192;
        const int lane = f2 & 63, t = f2 >> 6;
        const int nbl = t & 1, kk = (t >> 1) & 7, q4 = t >> 4;
        const int g = lane >> 4, c = lane & 15;
        const int n2 = 32 * q4 + 16 * nbl + c;
        #pragma unroll
        for (int j = 0; j < 8; ++j) v[j] = (__bf16)rhid2Layer[kinv(32 * kk + 8 * g + j) * 128 + n2];
        dst = ws + 131072 + (size_t)f2 * 16;
    } else if (f < 13312) {
        const int f3 = f - 12288;
        const int lane = f3 & 63, t = f3 >> 6;
        const int kk = t & 3, nb = t >> 2;
        const int g = lane >> 4, c = lane & 15;
        const int n3 = 16 * nb + c;
        #pragma unroll
        for (int j = 0; j < 8; ++j) v[j] = (__bf16)routLayer[(32 * kk + 8 * g + j) * 64 + n3];
        dst = ws + 196608 + (size_t)f3 * 16;
    } else {
        return;
    }
    *(bf16x8*)dst = v;
}

template<bool PRE>
__device__ __forceinline__ bf16x8 wfrag1(const char* ws, const float* WFOH, const float* WFOM,
                                         int w, int kk, int nbl, int lane) {
    if constexpr (PRE) {
        return *(const bf16x8*)(ws + (size_t)w * 16384 + kk * 2048 + nbl * 1024 + lane * 16);
    } else {
        const int g = lane >> 4, c = lane & 15;
        const int nb = 32 * w + 16 * nbl;
        const float* Wsrc = (nb < 128) ? WFOH : WFOM;
        const int col = (nb + c) & 127;
        bf16x8 v;
        #pragma unroll
        for (int j = 0; j < 8; ++j) v[j] = (__bf16)Wsrc[(32 * kk + 8 * g + j) * 128 + col];
        return v;
    }
}
template<bool PRE>
__device__ __forceinline__ bf16x8 wfrag2(const char* ws, const float* rhid2Layer,
                                         int q4, int kk, int nbl, int lane) {
    if constexpr (PRE) {
        return *(const bf16x8*)(ws + 131072 + (size_t)q4 * 16384 + kk * 2048 + nbl * 1024 + lane * 16);
    } else {
        const int g = lane >> 4, c = lane & 15;
        const int n2 = 32 * q4 + 16 * nbl + c;
        bf16x8 v;
        #pragma unroll
        for (int j = 0; j < 8; ++j) v[j] = (__bf16)rhid2Layer[kinv(32 * kk + 8 * g + j) * 128 + n2];
        return v;
    }
}
template<bool PRE>
__device__ __forceinline__ bf16x8 wfrag3(const char* ws, const float* routLayer,
                                         int nb, int kk, int lane) {
    if constexpr (PRE) {
        return *(const bf16x8*)(ws + 196608 + (size_t)nb * 4096 + kk * 1024 + lane * 16);
    } else {
        const int g = lane >> 4, c = lane & 15;
        const int n3 = 16 * nb + c;
        bf16x8 v;
        #pragma unroll
        for (int j = 0; j < 8; ++j) v[j] = (__bf16)routLayer[(32 * kk + 8 * g + j) * 64 + n3];
        return v;
    }
}

// M_TILE=64, 512 threads (8 waves), 64KB LDS (cat/h ping-pong, h2 aliased into
// current cat buffer) -> 2 blocks/CU with slack. Rotation swizzle
// (unit' = (unit+row)&mask) gives uniform-4 slot occupancy on every LDS
// access (optimal for ds_read_b128; the old XOR swizzle was 8-way).
// 3 barriers/tile; GEMM3+hinge fully in-wave (waves 0-3).
template<bool PRE>
__global__ __launch_bounds__(512, 2) void rel_kernel(
    const float* __restrict__ fwd, const float* __restrict__ bwd,
    const int* __restrict__ gold_heads, const int* __restrict__ gold_rels,
    const float* __restrict__ WFOH, const float* __restrict__ WFOM,
    const float* __restrict__ rcatBias, const float* __restrict__ rhid2Layer,
    const float* __restrict__ rhid2Bias, const float* __restrict__ routLayer,
    const float* __restrict__ routBias, const char* __restrict__ wstab,
    int* __restrict__ fixcnt, int* __restrict__ fixlist, int fixcap,
    float* __restrict__ out, int E, int NT)
{
    // Two 32KB buffers, ping-pong per tile: cat in one, h in the other.
    // h2 (64x256B = 16KB) aliases the current cat buffer (cat dead after GEMM1).
    __shared__ __align__(16) char smem[65536];

    const int tid   = threadIdx.x;
    const int w     = tid >> 6;
    const int lane  = tid & 63;
    const int row16 = lane & 15;
    const int g     = lane >> 4;

    const int r_s = tid >> 3;       // staging row (64 rows)
    const int q_s = tid & 7;        // staging eighth (32 floats = 4 units)

    const float rcb0 = rcatBias[32 * w + row16];
    const float rcb1 = rcatBias[32 * w + 16 + row16];
    const float r2b  = rhid2Bias[16 * w + row16];
    float rob[4];
    #pragma unroll
    for (int nb = 0; nb < 4; ++nb) rob[nb] = routBias[16 * nb + row16];

    // ---- prologue gather for first tile ----
    bf16x8 pfb[4];
    {
        const int e = blockIdx.x * 64 + r_s;
        int nh0 = 0;
        if (q_s < 4 && e < E) nh0 = gold_heads[e];
        if (e < E) {
            const float* src = (q_s < 4) ? (fwd + (size_t)nh0 * 128 + 32 * q_s)
                                         : (bwd + (size_t)(e + 1) * 128 + 32 * (q_s - 4));
            const float4* p4 = (const float4*)src;
            #pragma unroll
            for (int i = 0; i < 4; ++i) pfb[i] = cvt2(p4[2 * i], p4[2 * i + 1]);
        } else {
            #pragma unroll
            for (int i = 0; i < 4; ++i) pfb[i] = cvt2(make_float4(0.f,0.f,0.f,0.f), make_float4(0.f,0.f,0.f,0.f));
        }
    }

    int pp = 0;
    for (int tile = blockIdx.x; tile < NT; tile += gridDim.x, pp ^= 1) {
        char* const sh_cat = smem + (pp ? 32768 : 0);
        char* const sh_h   = smem + (pp ? 0 : 32768);
        char* const sh_h2  = sh_cat;       // alias (cat dead after GEMM1 k-loop)

        const int e0 = tile * 64;
        const int tnext = tile + gridDim.x;
        const bool hn = tnext < NT;

        // opaque-zero launder: prevents cross-tile frag hoisting (R7 spill)
        int zoff = 0;
        asm volatile("" : "+v"(zoff));
        const char*  wsL  = wstab + zoff;
        const float* W1aL = WFOH + zoff;
        const float* W1bL = WFOM + zoff;
        const float* W2L  = rhid2Layer + zoff;
        const float* W3L  = routLayer + zoff;

        // next tile's head index first (latency overlaps staging + B1 wait)
        int nh = 0; bool gv = false;
        if (hn) {
            const int en = tnext * 64 + r_s;
            gv = en < E;
            if (q_s < 4 && gv) nh = gold_heads[en];
        }

        // ---- stage cat tile (bf16, rotation-swizzled) from pfb ----
        // unit u = 4*q_s + i covers k in [32*q_s + 8i, +8); stored at (u+row)&31
        #pragma unroll
        for (int i = 0; i < 4; ++i)
            *(bf16x8*)(sh_cat + r_s * 512 + 16 * ((4 * q_s + i + r_s) & 31)) = pfb[i];

        // gold labels for this tile (hinge rows 16w + 4g + i)
        int gr[4] = {0, 0, 0, 0};
        if (w < 4) {
            #pragma unroll
            for (int i = 0; i < 4; ++i) {
                const int e = e0 + 16 * w + 4 * g + i;
                if (e < E) gr[i] = gold_rels[e];
            }
        }
        __syncthreads();                                   // B1: cat ready

        // ---- issue next tile's row gathers now; cvt before B3 ----
        float4 pfA[8];
        if (hn && gv) {
            const float4* p4 = (const float4*)((q_s < 4)
                                 ? (fwd + (size_t)nh * 128 + 32 * q_s)
                                 : (bwd + (size_t)(tnext * 64 + r_s + 1) * 128 + 32 * (q_s - 4)));
            #pragma unroll
            for (int i = 0; i < 8; ++i) pfA[i] = p4[i];
        } else {
            #pragma unroll
            for (int i = 0; i < 8; ++i) pfA[i] = make_float4(0.f, 0.f, 0.f, 0.f);
        }

        // ---- GEMM1: h(64x256) = cat @ [WFOH|WFOM], tanh(+rcatBias) ----
        f32x4 acc1[4][2];
        #pragma unroll
        for (int i = 0; i < 4; ++i) {
            acc1[i][0] = (f32x4){0.f, 0.f, 0.f, 0.f};
            acc1[i][1] = (f32x4){0.f, 0.f, 0.f, 0.f};
        }
        __builtin_amdgcn_s_setprio(1);
        #pragma unroll
        for (int kk = 0; kk < 8; ++kk) {
            const bf16x8 b0 = wfrag1<PRE>(wsL, W1aL, W1bL, w, kk, 0, lane);
            const bf16x8 b1 = wfrag1<PRE>(wsL, W1aL, W1bL, w, kk, 1, lane);
            #pragma unroll
            for (int mb = 0; mb < 4; ++mb) {
                const int R = 16 * mb + row16;
                const bf16x8 a = *(const bf16x8*)(sh_cat + R * 512 + 16 * ((4 * kk + g + R) & 31));
                acc1[mb][0] = MFMA16(a, b0, acc1[mb][0], 0, 0, 0);
                acc1[mb][1] = MFMA16(a, b1, acc1[mb][1], 0, 0, 0);
            }
        }
        __builtin_amdgcn_s_setprio(0);
        #pragma unroll
        for (int mb = 0; mb < 4; ++mb) {
            #pragma unroll
            for (int r = 0; r < 4; ++r) {
                const int row = 16 * mb + 4 * g + r;
                // kappa pair (cols 32w+row16, 32w+16+row16) -> stored bytes
                // [64w+4*row16, +4) of row; unit u = 4w + (row16>>2)
                const __bf16 p0 = (__bf16)fast_tanh(acc1[mb][0][r] + rcb0);
                const __bf16 p1 = (__bf16)fast_tanh(acc1[mb][1][r] + rcb1);
                const unsigned uval = (unsigned)__builtin_bit_cast(unsigned short, p0)
                                    | ((unsigned)__builtin_bit_cast(unsigned short, p1) << 16);
                const int u = 4 * w + (row16 >> 2);
                *(unsigned*)(sh_h + row * 512 + 16 * ((u + row) & 31) + 4 * (row16 & 3)) = uval;
            }
        }
        __syncthreads();                                   // B2: h ready

        // ---- GEMM2: h2(64x128) = h @ W2(kappa), tanh(+rhid2Bias) ----
        f32x4 acc2[4];
        #pragma unroll
        for (int i = 0; i < 4; ++i) acc2[i] = (f32x4){0.f, 0.f, 0.f, 0.f};
        __builtin_amdgcn_s_setprio(1);
        #pragma unroll
        for (int kk = 0; kk < 8; ++kk) {
            const bf16x8 b2 = wfrag2<PRE>(wsL, W2L, w >> 1, kk, w & 1, lane);
            #pragma unroll
            for (int mb = 0; mb < 4; ++mb) {
                const int R = 16 * mb + row16;
                const bf16x8 a = *(const bf16x8*)(sh_h + R * 512 + 16 * ((4 * kk + g + R) & 31));
                acc2[mb] = MFMA16(a, b2, acc2[mb], 0, 0, 0);
            }
        }
        __builtin_amdgcn_s_setprio(0);
        #pragma unroll
        for (int mb = 0; mb < 4; ++mb) {
            #pragma unroll
            for (int r = 0; r < 4; ++r) {
                const int row = 16 * mb + 4 * g + r;
                // identity col c = 16w + row16 -> byte 2c; unit u2 = 2w + (row16>>3)
                const __bf16 p = (__bf16)fast_tanh(acc2[mb][r] + r2b);
                const int u2 = 2 * w + (row16 >> 3);
                *(unsigned short*)(sh_h2 + row * 256 + 16 * ((u2 + row) & 15) + 2 * (row16 & 7))
                    = __builtin_bit_cast(unsigned short, p);
            }
        }
        // convert next-tile gather -> pfb (pfA issued before GEMM1: landed)
        #pragma unroll
        for (int i = 0; i < 4; ++i) pfb[i] = cvt2(pfA[2 * i], pfA[2 * i + 1]);
        __syncthreads();                                   // B3: h2 ready

        // ---- GEMM3 + hinge fully in-wave (waves 0-3; 16 rows x 64 labels) ----
        if (w < 4) {
            bf16x8 a3[4];
            #pragma unroll
            for (int kk = 0; kk < 4; ++kk) {
                const int R3 = 16 * w + row16;
                a3[kk] = *(const bf16x8*)(sh_h2 + R3 * 256 + 16 * ((4 * kk + g + R3) & 15));
            }
            f32x4 acc3[4];
            __builtin_amdgcn_s_setprio(1);
            #pragma unroll
            for (int nb = 0; nb < 4; ++nb) {
                acc3[nb] = (f32x4){0.f, 0.f, 0.f, 0.f};
                #pragma unroll
                for (int kk = 0; kk < 4; ++kk) {
                    const bf16x8 b = wfrag3<PRE>(wsL, W3L, nb, kk, lane);
                    acc3[nb] = MFMA16(a3[kk], b, acc3[nb], 0, 0, 0);
                }
            }
            __builtin_amdgcn_s_setprio(0);
            #pragma unroll
            for (int i = 0; i < 4; ++i) {
                const int gold = gr[i];
                float gs = -3.0e38f, ws_ = -3.0e38f;
                #pragma unroll
                for (int nb = 0; nb < 4; ++nb) {
                    const float v = acc3[nb][i] + rob[nb];
                    const int lab = 16 * nb + row16;
                    if (lab == gold) gs = v; else ws_ = fmaxf(ws_, v);
                }
                gs = fmaxf(gs, __shfl_xor(gs, 1)); ws_ = fmaxf(ws_, __shfl_xor(ws_, 1));
                gs = fmaxf(gs, __shfl_xor(gs, 2)); ws_ = fmaxf(ws_, __shfl_xor(ws_, 2));
                gs = fmaxf(gs, __shfl_xor(gs, 4)); ws_ = fmaxf(ws_, __shfl_xor(ws_, 4));
                gs = fmaxf(gs, __shfl_xor(gs, 8)); ws_ = fmaxf(ws_, __shfl_xor(ws_, 8));
                const int e = e0 + 16 * w + 4 * g + i;
                if (row16 == 0 && e < E) {
                    out[e] = (gs < ws_ + 1.0f) ? (ws_ - gs) : 0.0f;
                    // hinge discontinuous at margin==1 -> exact f32 recompute
                    if (fabsf((gs - ws_) - 1.0f) < 0.125f && fixcap > 0) {
                        const int idx = atomicAdd(fixcnt, 1);
                        if (idx < fixcap) fixlist[idx] = e;
                    }
                }
            }
        }
        // no end barrier: next staging writes the OTHER buffer (= this tile's h,
        // dead since GEMM2 k-loop, ordered by B3); h2 readers are unaffected.
    }
}

// ---- exact f32 recompute of margin-boundary edges (~1e-3 of edges) ----
__global__ __launch_bounds__(256) void fixup_kernel(
    const float* __restrict__ fwd, const float* __restrict__ bwd,
    const int* __restrict__ gold_heads, const int* __restrict__ gold_rels,
    const float* __restrict__ WFOH, const float* __restrict__ WFOM,
    const float* __restrict__ rcatBias, const float* __restrict__ rhid2Layer,
    const float* __restrict__ rhid2Bias, const float* __restrict__ routLayer,
    const float* __restrict__ routBias,
    const int* __restrict__ fixcnt, const int* __restrict__ fixlist, int fixcap,
    float* __restrict__ out)
{
    __shared__ float fx_cat[256];
    __shared__ float fx_h[256];
    __shared__ float fx_h2[128];
    __shared__ float fx_p[256];
    int n = *fixcnt;
    if (n > fixcap) n = fixcap;
    const int tid = threadIdx.x;
    for (int i = blockIdx.x; i < n; i += gridDim.x) {
        const int e = fixlist[i];
        {
            const int head = gold_heads[e];
            fx_cat[tid] = (tid < 128) ? fwd[(size_t)head * 128 + tid]
                                      : bwd[(size_t)(e + 1) * 128 + (tid - 128)];
        }
        __syncthreads();
        {
            const float* base = (tid < 128) ? WFOH : WFOM;
            const int col = tid & 127;
            float s = 0.f;
            #pragma unroll 8
            for (int k = 0; k < 256; ++k) s += fx_cat[k] * base[k * 128 + col];
            fx_h[tid] = tanhf(s + rcatBias[tid]);
        }
        __syncthreads();
        {
            const int d = tid & 127, hh = tid >> 7;
            float s = 0.f;
            #pragma unroll 8
            for (int k = 128 * hh; k < 128 * hh + 128; ++k) s += fx_h[k] * rhid2Layer[k * 128 + d];
            fx_p[hh * 128 + d] = s;
        }
        __syncthreads();
        if (tid < 128) fx_h2[tid] = tanhf(fx_p[tid] + fx_p[128 + tid] + rhid2Bias[tid]);
        __syncthreads();
        {
            const int d = tid & 63, qq = tid >> 6;
            float s = 0.f;
            #pragma unroll 8
            for (int k = 32 * qq; k < 32 * qq + 32; ++k) s += fx_h2[k] * routLayer[k * 64 + d];
            fx_p[qq * 64 + d] = s;
        }
        __syncthreads();
        if (tid < 64) {
            const float v = fx_p[tid] + fx_p[64 + tid] + fx_p[128 + tid] + fx_p[192 + tid] + routBias[tid];
            const int gold = gold_rels[e];
            float gs = (tid == gold) ? v : -3.0e38f;
            float wv = (tid == gold) ? -3.0e38f : v;
            #pragma unroll
            for (int o = 1; o < 64; o <<= 1) {
                gs = fmaxf(gs, __shfl_xor(gs, o));
                wv = fmaxf(wv, __shfl_xor(wv, o));
            }
            if (tid == 0) out[e] = (gs < wv + 1.0f) ? (wv - gs) : 0.0f;
        }
        __syncthreads();
    }
}

extern "C" void kernel_launch(void* const* d_in, const int* in_sizes, int n_in,
                              void* d_out, int out_size, void* d_ws, size_t ws_size,
                              hipStream_t stream) {
    const float* fwd        = (const float*)d_in[0];
    const float* bwd        = (const float*)d_in[1];
    const int*   gold_heads = (const int*)d_in[2];
    const int*   gold_rels  = (const int*)d_in[3];
    const float* WFOH       = (const float*)d_in[4];
    const float* WFOM       = (const float*)d_in[5];
    const float* rcatBias   = (const float*)d_in[7];   // d_in[6] rhidBias unused by reference
    const float* rhid2      = (const float*)d_in[8];
    const float* rhid2Bias  = (const float*)d_in[9];
    const float* rout       = (const float*)d_in[10];
    const float* routBias   = (const float*)d_in[11];
    float* out = (float*)d_out;

    const int E = in_sizes[2];
    if (E <= 0) return;
    const int NT = (E + 63) / 64;
    const int grid = NT < 512 ? NT : 512;

    const size_t TAB = 212992;
    const int FIXCAP = 8192;
    const size_t FIX_BYTES = 4 + 4 * (size_t)FIXCAP;

    const bool pre = ws_size >= TAB + FIX_BYTES;
    int* fixcnt = nullptr;
    int* fixlist = nullptr;
    int fixcap = 0;
    if (pre) {
        fixcnt = (int*)((char*)d_ws + TAB);
        fixlist = fixcnt + 1;
        fixcap = FIXCAP;
    } else if (ws_size >= FIX_BYTES) {
        fixcnt = (int*)d_ws;
        fixlist = fixcnt + 1;
        fixcap = FIXCAP;
    }
    if (fixcap) hipMemsetAsync(fixcnt, 0, 4, stream);

    if (pre) {
        hipLaunchKernelGGL(preconv_kernel, dim3(52), dim3(256), 0, stream,
                           WFOH, WFOM, rhid2, rout, (char*)d_ws);
        hipLaunchKernelGGL((rel_kernel<true>), dim3(grid), dim3(512), 0, stream,
                           fwd, bwd, gold_heads, gold_rels, WFOH, WFOM, rcatBias,
                           rhid2, rhid2Bias, rout, routBias, (const char*)d_ws,
                           fixcnt, fixlist, fixcap, out, E, NT);
    } else {
        hipLaunchKernelGGL((rel_kernel<false>), dim3(grid), dim3(512), 0, stream,
                           fwd, bwd, gold_heads, gold_rels, WFOH, WFOM, rcatBias,
                           rhid2, rhid2Bias, rout, routBias, (const char*)nullptr,
                           fixcnt, fixlist, fixcap, out, E, NT);
    }
    if (fixcap) {
        hipLaunchKernelGGL(fixup_kernel, dim3(120), dim3(256), 0, stream,
                           fwd, bwd, gold_heads, gold_rels, WFOH, WFOM, rcatBias,
                           rhid2, rhid2Bias, rout, routBias,
                           fixcnt, fixlist, fixcap, out);
    }
}